// Round 2
// baseline (5490.424 us; speedup 1.0000x reference)
//
#include <hip/hip_runtime.h>

typedef __attribute__((ext_vector_type(8))) short short8;
typedef __attribute__((ext_vector_type(4))) float f32x4;

#define DD 128
#define HH 256

__device__ __forceinline__ unsigned short f2bf(float f) {
  unsigned int u = __float_as_uint(f);
  u += 0x7fffu + ((u >> 16) & 1u);
  return (unsigned short)(u >> 16);
}
__device__ __forceinline__ float bf2f(unsigned short s) {
  return __uint_as_float(((unsigned int)s) << 16);
}

__device__ __forceinline__ f32x4 mfma16(short8 a, short8 b, f32x4 c) {
  return __builtin_amdgcn_mfma_f32_16x16x32_bf16(a, b, c, 0, 0, 0);
}

// ---- weight convert: dst[n][k] = bf16(src[(k+kswap)%K][n]), src row stride = Nout
__global__ void wconv(const float* __restrict__ src, unsigned short* __restrict__ dst,
                      int K, int Nout, int kswap) {
  int id = blockIdx.x * 256 + threadIdx.x;
  if (id >= K * Nout) return;
  int n = id / K, k = id - n * K;
  int ks = k + kswap; if (ks >= K) ks -= K;
  dst[n * K + k] = f2bf(src[(size_t)ks * Nout + n]);
}

// ---- edge vectors + fold edge constants into layer-1 biases (1 block, 256 thr)
__global__ void prep_bias(const float* __restrict__ Ew1, const float* __restrict__ Eb1,
                          const float* __restrict__ Ew2, const float* __restrict__ Eb2,
                          const float* __restrict__ Pw1, const float* __restrict__ Pb1,
                          const float* __restrict__ Cw1, const float* __restrict__ Cb1,
                          float* __restrict__ b1P, float* __restrict__ b1C) {
  __shared__ float h1[HH], h0[HH], ein[DD], eout[DD];
  int t = threadIdx.x;
  h1[t] = fmaxf(Ew1[t] + Eb1[t], 0.f);  // MLP_E(ones) layer1
  h0[t] = fmaxf(Eb1[t], 0.f);           // MLP_E(zeros) layer1
  __syncthreads();
  if (t < DD) {
    float s1 = Eb2[t], s0 = Eb2[t];
    for (int j = 0; j < HH; ++j) { s1 += h1[j] * Ew2[j * DD + t]; s0 += h0[j] * Ew2[j * DD + t]; }
    ein[t]  = fmaxf(s1, 0.f);
    eout[t] = fmaxf(s0, 0.f);
  }
  __syncthreads();
  float bp = Pb1[t], bc = Cb1[t];
  for (int d = 0; d < DD; ++d) {
    bp += eout[d] * Pw1[(size_t)(256 + d) * HH + t];
    bc += ein[d]  * Cw1[(size_t)(256 + d) * HH + t];
  }
  b1P[t] = bp; b1C[t] = bc;
}

// ---- bucket edges per node as linked lists (no scan needed)
__global__ void build_list(const int* __restrict__ selfI, const int* __restrict__ parI,
                           int* headP, int* nextP, int* headC, int* nextC, int E) {
  int id = blockIdx.x * 256 + threadIdx.x;
  if (id < E) {
    nextP[id] = atomicExch(&headP[selfI[id]], id);
    nextC[id] = atomicExch(&headC[parI[id]], id);
  }
}

// ---- MLP_V: hidden = relu(relu(x@W1+b1)@W2+b2), K=128 -> 256 -> 128
__global__ __launch_bounds__(256) void v_kernel(
    const float* __restrict__ x, const unsigned short* __restrict__ W1t,
    const unsigned short* __restrict__ W2t, const float* __restrict__ b1,
    const float* __restrict__ b2, float* __restrict__ hidden, int n) {
  __shared__ __align__(16) unsigned short A[64 * 136];
  __shared__ __align__(16) unsigned short O1[64 * 264];
  int t = threadIdx.x;
  int w = t >> 6, lane = t & 63, ln = lane & 15, quad = lane >> 4, qo = quad * 8;
  long tile0 = (long)blockIdx.x * 64;
  int rl = t >> 2, part = t & 3;
  long gr = tile0 + rl;
  const float* src = x + (size_t)(gr < n ? gr : 0) * DD + part * 32;
  unsigned short* arow = A + rl * 136 + part * 32;
#pragma unroll
  for (int i = 0; i < 8; ++i) {
    float4 v = *(const float4*)(src + i * 4);
    *(ushort4*)(arow + i * 4) = make_ushort4(f2bf(v.x), f2bf(v.y), f2bf(v.z), f2bf(v.w));
  }
  const unsigned short* aRow = A + (w * 16 + ln) * 136;
  f32x4 zero4 = {0.f, 0.f, 0.f, 0.f};
  f32x4 acc1[16];
#pragma unroll
  for (int nt = 0; nt < 16; ++nt) acc1[nt] = zero4;
#pragma unroll
  for (int kt = 0; kt < 4; ++kt) {
    short8 a = *(const short8*)(aRow + kt * 32 + qo);
#pragma unroll
    for (int nt = 0; nt < 16; ++nt) {
      short8 b = *(const short8*)(W1t + (size_t)(nt * 16 + ln) * 128 + kt * 32 + qo);
      acc1[nt] = mfma16(a, b, acc1[nt]);
    }
  }
#pragma unroll
  for (int nt = 0; nt < 16; ++nt) {
    float bb = b1[nt * 16 + ln];
#pragma unroll
    for (int r = 0; r < 4; ++r)
      O1[(w * 16 + quad * 4 + r) * 264 + nt * 16 + ln] = f2bf(fmaxf(acc1[nt][r] + bb, 0.f));
  }
  const unsigned short* oRow = O1 + (w * 16 + ln) * 264;
  f32x4 acc2[8];
#pragma unroll
  for (int nt = 0; nt < 8; ++nt) acc2[nt] = zero4;
#pragma unroll
  for (int kt = 0; kt < 8; ++kt) {
    short8 a = *(const short8*)(oRow + kt * 32 + qo);
#pragma unroll
    for (int nt = 0; nt < 8; ++nt) {
      short8 b = *(const short8*)(W2t + (size_t)(nt * 16 + ln) * 256 + kt * 32 + qo);
      acc2[nt] = mfma16(a, b, acc2[nt]);
    }
  }
#pragma unroll
  for (int nt = 0; nt < 8; ++nt) {
    float bb = b2[nt * 16 + ln];
#pragma unroll
    for (int r = 0; r < 4; ++r) {
      long gr2 = tile0 + w * 16 + quad * 4 + r;
      if (gr2 < n) hidden[gr2 * DD + nt * 16 + ln] = fmaxf(acc2[nt][r] + bb, 0.f);
    }
  }
}

// ---- one edge MLP (K=256 -> 256 -> 128), A-frags preloaded in registers,
//      layer-1 output overlaid on the (dead) A-tile rows (wave-private, no barrier)
__device__ __forceinline__ void edge_mlp(const short8* aF, unsigned short* SA,
                                         int w, int ln, int quad, int qo,
                                         const unsigned short* __restrict__ W1t,
                                         const float* __restrict__ b1,
                                         const unsigned short* __restrict__ W2t,
                                         f32x4* acc2) {
  f32x4 zero4 = {0.f, 0.f, 0.f, 0.f};
  f32x4 acc1[16];
#pragma unroll
  for (int nt = 0; nt < 16; ++nt) acc1[nt] = zero4;
#pragma unroll
  for (int kt = 0; kt < 8; ++kt) {
#pragma unroll
    for (int nt = 0; nt < 16; ++nt) {
      short8 b = *(const short8*)(W1t + (size_t)(nt * 16 + ln) * 256 + kt * 32 + qo);
      acc1[nt] = mfma16(aF[kt], b, acc1[nt]);
    }
  }
#pragma unroll
  for (int nt = 0; nt < 16; ++nt) {
    float bb = b1[nt * 16 + ln];
#pragma unroll
    for (int r = 0; r < 4; ++r)
      SA[(w * 16 + quad * 4 + r) * 264 + nt * 16 + ln] = f2bf(fmaxf(acc1[nt][r] + bb, 0.f));
  }
  const unsigned short* oRow = (const unsigned short*)SA + (w * 16 + ln) * 264;
#pragma unroll
  for (int nt = 0; nt < 8; ++nt) acc2[nt] = zero4;
#pragma unroll
  for (int kt = 0; kt < 8; ++kt) {
    short8 a = *(const short8*)(oRow + kt * 32 + qo);
#pragma unroll
    for (int nt = 0; nt < 8; ++nt) {
      short8 b = *(const short8*)(W2t + (size_t)(nt * 16 + ln) * 256 + kt * 32 + qo);
      acc2[nt] = mfma16(a, b, acc2[nt]);
    }
  }
}

// ---- per-hop edge kernel: gather [hs|hp], P-MLP + C-MLP, store bf16 rows [E,128]
__global__ __launch_bounds__(256) void edge_kernel(
    const float* __restrict__ hidden, const int* __restrict__ selfI, const int* __restrict__ parI,
    const unsigned short* __restrict__ Pw1t, const unsigned short* __restrict__ Pw2t,
    const unsigned short* __restrict__ Cw1t, const unsigned short* __restrict__ Cw2t,
    const float* __restrict__ b1P, const float* __restrict__ b1C,
    const float* __restrict__ b2P, const float* __restrict__ b2C,
    unsigned short* __restrict__ SpE, unsigned short* __restrict__ ScE, int E) {
  __shared__ __align__(16) unsigned short SA[64 * 264];
  int t = threadIdx.x;
  int w = t >> 6, lane = t & 63, ln = lane & 15, quad = lane >> 4, qo = quad * 8;
  long tile0 = (long)blockIdx.x * 64;
  int rl = t >> 2, part = t & 3;
  long ge = tile0 + rl;
  int si = (ge < E) ? selfI[ge] : 0;
  int pi = (ge < E) ? parI[ge] : 0;
  const float* hs = hidden + (size_t)si * DD + part * 32;
  const float* hp = hidden + (size_t)pi * DD + part * 32;
  unsigned short* arow = SA + rl * 264;
#pragma unroll
  for (int i = 0; i < 8; ++i) {
    float4 v = *(const float4*)(hs + i * 4);
    *(ushort4*)(arow + part * 32 + i * 4) =
        make_ushort4(f2bf(v.x), f2bf(v.y), f2bf(v.z), f2bf(v.w));
    float4 u = *(const float4*)(hp + i * 4);
    *(ushort4*)(arow + 128 + part * 32 + i * 4) =
        make_ushort4(f2bf(u.x), f2bf(u.y), f2bf(u.z), f2bf(u.w));
  }
  // preload A-fragments so the LDS tile can be reused for O1 / output repack
  const unsigned short* aRow = SA + (w * 16 + ln) * 264;
  short8 aF[8];
#pragma unroll
  for (int kt = 0; kt < 8; ++kt) aF[kt] = *(const short8*)(aRow + kt * 32 + qo);

  f32x4 acc2[8];
  // P: input [hp|hs|eo] realized as [hs|hp] @ half-swapped Pw1 (+ folded bias)
  edge_mlp(aF, SA, w, ln, quad, qo, Pw1t, b1P, Pw2t, acc2);
  // repack C-layout -> row-major bf16 in SA (cols 0..127), then coalesced store
#pragma unroll
  for (int nt = 0; nt < 8; ++nt) {
    float bb = b2P[nt * 16 + ln];
#pragma unroll
    for (int r = 0; r < 4; ++r)
      SA[(w * 16 + quad * 4 + r) * 264 + nt * 16 + ln] = f2bf(fmaxf(acc2[nt][r] + bb, 0.f));
  }
  if (ge < E) {
    const unsigned short* srow = SA + rl * 264 + part * 32;
    ushort4* dst = (ushort4*)(SpE + (size_t)ge * 128 + part * 32);
#pragma unroll
    for (int i = 0; i < 8; ++i) dst[i] = *(const ushort4*)(srow + i * 4);
  }
  // C: input [hs|hp|ei] directly
  edge_mlp(aF, SA, w, ln, quad, qo, Cw1t, b1C, Cw2t, acc2);
#pragma unroll
  for (int nt = 0; nt < 8; ++nt) {
    float bb = b2C[nt * 16 + ln];
#pragma unroll
    for (int r = 0; r < 4; ++r)
      SA[(w * 16 + quad * 4 + r) * 264 + nt * 16 + ln] = f2bf(fmaxf(acc2[nt][r] + bb, 0.f));
  }
  if (ge < E) {
    const unsigned short* srow = SA + rl * 264 + part * 32;
    ushort4* dst = (ushort4*)(ScE + (size_t)ge * 128 + part * 32);
#pragma unroll
    for (int i = 0; i < 8; ++i) dst[i] = *(const ushort4*)(srow + i * 4);
  }
}

// ---- per-hop node kernel: gather-mean via lists, build [h|S_p|S_c], MLP_A, residual
__global__ __launch_bounds__(256) void node_kernel(
    float* __restrict__ hidden,
    const unsigned short* __restrict__ SpE, const unsigned short* __restrict__ ScE,
    const int* __restrict__ headP, const int* __restrict__ nextP,
    const int* __restrict__ headC, const int* __restrict__ nextC,
    const float* __restrict__ rootM, const float* __restrict__ leafM,
    const float* __restrict__ startT, const float* __restrict__ endT,
    const unsigned short* __restrict__ W1t, const unsigned short* __restrict__ W2t,
    const float* __restrict__ b1, const float* __restrict__ b2, int n) {
  __shared__ __align__(16) unsigned short SA[64 * 392];
  int t = threadIdx.x;
  int w = t >> 6, lane = t & 63, ln = lane & 15, quad = lane >> 4, qo = quad * 8;
  long tile0 = (long)blockIdx.x * 64;
  int rl = t >> 2, part = t & 3;
  int c0 = part * 32;
  long gr = tile0 + rl;
  long g = (gr < n) ? gr : 0;
  float rm = rootM[g], lm = leafM[g];
  unsigned short* arow = SA + rl * 392;
  const float* hrow = hidden + (size_t)g * DD + c0;
#pragma unroll
  for (int i = 0; i < 8; ++i) {
    float4 h = *(const float4*)(hrow + i * 4);
    *(ushort4*)(arow + c0 + i * 4) = make_ushort4(f2bf(h.x), f2bf(h.y), f2bf(h.z), f2bf(h.w));
  }
  {
    float s[32];
#pragma unroll
    for (int i = 0; i < 32; ++i) s[i] = 0.f;
    int cnt = 0;
    for (int e = headP[g]; e >= 0; e = nextP[e]) {
      const unsigned short* rr = SpE + (size_t)e * 128 + c0;
#pragma unroll
      for (int i = 0; i < 8; ++i) {
        ushort4 u = *(const ushort4*)(rr + i * 4);
        s[i * 4 + 0] += bf2f(u.x); s[i * 4 + 1] += bf2f(u.y);
        s[i * 4 + 2] += bf2f(u.z); s[i * 4 + 3] += bf2f(u.w);
      }
      cnt++;
    }
    float ip = 1.f / fmaxf((float)cnt, 1.f);
#pragma unroll
    for (int i = 0; i < 8; ++i) {
      float4 st = *(const float4*)(startT + c0 + i * 4);
      *(ushort4*)(arow + 128 + c0 + i * 4) = make_ushort4(
          f2bf(s[i * 4 + 0] * ip + rm * st.x), f2bf(s[i * 4 + 1] * ip + rm * st.y),
          f2bf(s[i * 4 + 2] * ip + rm * st.z), f2bf(s[i * 4 + 3] * ip + rm * st.w));
    }
#pragma unroll
    for (int i = 0; i < 32; ++i) s[i] = 0.f;
    cnt = 0;
    for (int e = headC[g]; e >= 0; e = nextC[e]) {
      const unsigned short* rr = ScE + (size_t)e * 128 + c0;
#pragma unroll
      for (int i = 0; i < 8; ++i) {
        ushort4 u = *(const ushort4*)(rr + i * 4);
        s[i * 4 + 0] += bf2f(u.x); s[i * 4 + 1] += bf2f(u.y);
        s[i * 4 + 2] += bf2f(u.z); s[i * 4 + 3] += bf2f(u.w);
      }
      cnt++;
    }
    float ic = 1.f / fmaxf((float)cnt, 1.f);
#pragma unroll
    for (int i = 0; i < 8; ++i) {
      float4 et = *(const float4*)(endT + c0 + i * 4);
      *(ushort4*)(arow + 256 + c0 + i * 4) = make_ushort4(
          f2bf(s[i * 4 + 0] * ic + lm * et.x), f2bf(s[i * 4 + 1] * ic + lm * et.y),
          f2bf(s[i * 4 + 2] * ic + lm * et.z), f2bf(s[i * 4 + 3] * ic + lm * et.w));
    }
  }
  const unsigned short* aRow = SA + (w * 16 + ln) * 392;
  f32x4 zero4 = {0.f, 0.f, 0.f, 0.f};
  f32x4 acc1[16];
#pragma unroll
  for (int nt = 0; nt < 16; ++nt) acc1[nt] = zero4;
#pragma unroll
  for (int kt = 0; kt < 12; ++kt) {
    short8 a = *(const short8*)(aRow + kt * 32 + qo);
#pragma unroll
    for (int nt = 0; nt < 16; ++nt) {
      short8 b = *(const short8*)(W1t + (size_t)(nt * 16 + ln) * 384 + kt * 32 + qo);
      acc1[nt] = mfma16(a, b, acc1[nt]);
    }
  }
  // O1 overlaid on own rows (stride 392, cols 0..255) — wave-private, no barrier
#pragma unroll
  for (int nt = 0; nt < 16; ++nt) {
    float bb = b1[nt * 16 + ln];
#pragma unroll
    for (int r = 0; r < 4; ++r)
      SA[(w * 16 + quad * 4 + r) * 392 + nt * 16 + ln] = f2bf(fmaxf(acc1[nt][r] + bb, 0.f));
  }
  const unsigned short* oRow = SA + (w * 16 + ln) * 392;
  f32x4 acc2[8];
#pragma unroll
  for (int nt = 0; nt < 8; ++nt) acc2[nt] = zero4;
#pragma unroll
  for (int kt = 0; kt < 8; ++kt) {
    short8 a = *(const short8*)(oRow + kt * 32 + qo);
#pragma unroll
    for (int nt = 0; nt < 8; ++nt) {
      short8 b = *(const short8*)(W2t + (size_t)(nt * 16 + ln) * 256 + kt * 32 + qo);
      acc2[nt] = mfma16(a, b, acc2[nt]);
    }
  }
#pragma unroll
  for (int nt = 0; nt < 8; ++nt) {
    float bb = b2[nt * 16 + ln];
#pragma unroll
    for (int r = 0; r < 4; ++r) {
      long gr2 = tile0 + w * 16 + quad * 4 + r;
      if (gr2 < n) {
        size_t o = (size_t)gr2 * DD + nt * 16 + ln;
        hidden[o] = hidden[o] + fmaxf(acc2[nt][r] + bb, 0.f);
      }
    }
  }
}

extern "C" void kernel_launch(void* const* d_in, const int* in_sizes, int n_in,
                              void* d_out, int out_size, void* d_ws, size_t ws_size,
                              hipStream_t stream) {
  const float* batch  = (const float*)d_in[0];
  const int*   selfI  = (const int*)d_in[1];
  const int*   parI   = (const int*)d_in[2];
  const float* rootM  = (const float*)d_in[3];
  const float* leafM  = (const float*)d_in[4];
  const float* startT = (const float*)d_in[5];
  const float* endT   = (const float*)d_in[6];
  const float* Vw1 = (const float*)d_in[7],  *Vb1 = (const float*)d_in[8];
  const float* Vw2 = (const float*)d_in[9],  *Vb2 = (const float*)d_in[10];
  const float* Ew1 = (const float*)d_in[11], *Eb1 = (const float*)d_in[12];
  const float* Ew2 = (const float*)d_in[13], *Eb2 = (const float*)d_in[14];
  const float* Pw1 = (const float*)d_in[15], *Pb1 = (const float*)d_in[16];
  const float* Pw2 = (const float*)d_in[17], *Pb2 = (const float*)d_in[18];
  const float* Cw1 = (const float*)d_in[19], *Cb1 = (const float*)d_in[20];
  const float* Cw2 = (const float*)d_in[21], *Cb2 = (const float*)d_in[22];
  const float* Aw1 = (const float*)d_in[23], *Ab1 = (const float*)d_in[24];
  const float* Aw2 = (const float*)d_in[25], *Ab2 = (const float*)d_in[26];

  const int N = in_sizes[3];
  const int E = in_sizes[1];
  float* out = (float*)d_out;

  char* p = (char*)d_ws;
  auto nxt = [&](size_t sz) { char* r = p; p += (sz + 255) & ~(size_t)255; return r; };
  unsigned short* SpE = (unsigned short*)nxt((size_t)E * DD * 2);
  unsigned short* ScE = (unsigned short*)nxt((size_t)E * DD * 2);
  int* headP = (int*)nxt((size_t)N * 4);
  int* headC = (int*)nxt((size_t)N * 4);
  int* nextP = (int*)nxt((size_t)E * 4);
  int* nextC = (int*)nxt((size_t)E * 4);
  unsigned short* Vw1t = (unsigned short*)nxt((size_t)128 * 256 * 2);
  unsigned short* Vw2t = (unsigned short*)nxt((size_t)256 * 128 * 2);
  unsigned short* Pw1t = (unsigned short*)nxt((size_t)256 * 256 * 2);
  unsigned short* Pw2t = (unsigned short*)nxt((size_t)256 * 128 * 2);
  unsigned short* Cw1t = (unsigned short*)nxt((size_t)256 * 256 * 2);
  unsigned short* Cw2t = (unsigned short*)nxt((size_t)256 * 128 * 2);
  unsigned short* Aw1t = (unsigned short*)nxt((size_t)384 * 256 * 2);
  unsigned short* Aw2t = (unsigned short*)nxt((size_t)256 * 128 * 2);
  float* b1P = (float*)nxt(256 * 4);
  float* b1C = (float*)nxt(256 * 4);
  // total ws usage ~133 MB

  hipMemsetAsync(headP, 0xFF, (size_t)N * 4, stream);
  hipMemsetAsync(headC, 0xFF, (size_t)N * 4, stream);

  auto blk = [](int total) { return dim3((total + 255) / 256); };
  wconv<<<blk(128 * 256), 256, 0, stream>>>(Vw1, Vw1t, 128, 256, 0);
  wconv<<<blk(256 * 128), 256, 0, stream>>>(Vw2, Vw2t, 256, 128, 0);
  wconv<<<blk(256 * 256), 256, 0, stream>>>(Pw1, Pw1t, 256, 256, 128); // half-swap
  wconv<<<blk(256 * 128), 256, 0, stream>>>(Pw2, Pw2t, 256, 128, 0);
  wconv<<<blk(256 * 256), 256, 0, stream>>>(Cw1, Cw1t, 256, 256, 0);
  wconv<<<blk(256 * 128), 256, 0, stream>>>(Cw2, Cw2t, 256, 128, 0);
  wconv<<<blk(384 * 256), 256, 0, stream>>>(Aw1, Aw1t, 384, 256, 0);
  wconv<<<blk(256 * 128), 256, 0, stream>>>(Aw2, Aw2t, 256, 128, 0);

  prep_bias<<<1, 256, 0, stream>>>(Ew1, Eb1, Ew2, Eb2, Pw1, Pb1, Cw1, Cb1, b1P, b1C);
  build_list<<<blk(E), 256, 0, stream>>>(selfI, parI, headP, nextP, headC, nextC, E);

  dim3 gN((N + 63) / 64), gE((E + 63) / 64);
  v_kernel<<<gN, 256, 0, stream>>>(batch, Vw1t, Vw2t, Vb1, Vb2, out, N);

  for (int hop = 0; hop < 3; ++hop) {
    edge_kernel<<<gE, 256, 0, stream>>>(out, selfI, parI, Pw1t, Pw2t, Cw1t, Cw2t,
                                        b1P, b1C, Pb2, Cb2, SpE, ScE, E);
    node_kernel<<<gN, 256, 0, stream>>>(out, SpE, ScE, headP, nextP, headC, nextC,
                                        rootM, leafM, startT, endT, Aw1t, Aw2t, Ab1, Ab2, N);
  }
}

// Round 3
// 1953.889 us; speedup vs baseline: 2.8100x; 2.8100x over previous
//
#include <hip/hip_runtime.h>

typedef __attribute__((ext_vector_type(8))) short short8;
typedef __attribute__((ext_vector_type(4))) float f32x4;

#define DD 128
#define HH 256

__device__ __forceinline__ unsigned short f2bf(float f) {
  unsigned int u = __float_as_uint(f);
  u += 0x7fffu + ((u >> 16) & 1u);
  return (unsigned short)(u >> 16);
}
__device__ __forceinline__ float bf2f(unsigned short s) {
  return __uint_as_float(((unsigned int)s) << 16);
}
__device__ __forceinline__ f32x4 mfma16(short8 a, short8 b, f32x4 c) {
  return __builtin_amdgcn_mfma_f32_16x16x32_bf16(a, b, c, 0, 0, 0);
}

// ---- weight convert: dst[n][k] = bf16(src[(k+kswap)%K][n]), src row stride = Nout
__global__ void wconv(const float* __restrict__ src, unsigned short* __restrict__ dst,
                      int K, int Nout, int kswap) {
  int id = blockIdx.x * 256 + threadIdx.x;
  if (id >= K * Nout) return;
  int n = id / K, k = id - n * K;
  int ks = k + kswap; if (ks >= K) ks -= K;
  dst[n * K + k] = f2bf(src[(size_t)ks * Nout + n]);
}

// ---- edge vectors + fold edge constants into layer-1 biases (1 block, 256 thr)
__global__ void prep_bias(const float* __restrict__ Ew1, const float* __restrict__ Eb1,
                          const float* __restrict__ Ew2, const float* __restrict__ Eb2,
                          const float* __restrict__ Pw1, const float* __restrict__ Pb1,
                          const float* __restrict__ Cw1, const float* __restrict__ Cb1,
                          float* __restrict__ b1P, float* __restrict__ b1C) {
  __shared__ float h1[HH], h0[HH], ein[DD], eout[DD];
  int t = threadIdx.x;
  h1[t] = fmaxf(Ew1[t] + Eb1[t], 0.f);
  h0[t] = fmaxf(Eb1[t], 0.f);
  __syncthreads();
  if (t < DD) {
    float s1 = Eb2[t], s0 = Eb2[t];
    for (int j = 0; j < HH; ++j) { s1 += h1[j] * Ew2[j * DD + t]; s0 += h0[j] * Ew2[j * DD + t]; }
    ein[t]  = fmaxf(s1, 0.f);
    eout[t] = fmaxf(s0, 0.f);
  }
  __syncthreads();
  float bp = Pb1[t], bc = Cb1[t];
  for (int d = 0; d < DD; ++d) {
    bp += eout[d] * Pw1[(size_t)(256 + d) * HH + t];
    bc += ein[d]  * Cw1[(size_t)(256 + d) * HH + t];
  }
  b1P[t] = bp; b1C[t] = bc;
}

// ---- CSR build: degree count, 3-kernel exclusive scan, per-edge position
__global__ void count_k(const int* __restrict__ selfI, const int* __restrict__ parI,
                        int* degP, int* degC, int E) {
  int id = blockIdx.x * 256 + threadIdx.x;
  if (id < E) { atomicAdd(&degP[selfI[id]], 1); atomicAdd(&degC[parI[id]], 1); }
}

__global__ void scan1(const int* __restrict__ src, int* __restrict__ dst,
                      int* __restrict__ part, int n) {
  __shared__ int sh[256];
  int t = threadIdx.x;
  int base = blockIdx.x * 1024 + t * 4;
  int v0 = base + 0 < n ? src[base + 0] : 0;
  int v1 = base + 1 < n ? src[base + 1] : 0;
  int v2 = base + 2 < n ? src[base + 2] : 0;
  int v3 = base + 3 < n ? src[base + 3] : 0;
  int tsum = v0 + v1 + v2 + v3;
  sh[t] = tsum;
  __syncthreads();
  for (int off = 1; off < 256; off <<= 1) {
    int y = (t >= off) ? sh[t - off] : 0;
    __syncthreads();
    if (t >= off) sh[t] += y;
    __syncthreads();
  }
  int ex = sh[t] - tsum;
  if (base + 0 < n) dst[base + 0] = ex;
  if (base + 1 < n) dst[base + 1] = ex + v0;
  if (base + 2 < n) dst[base + 2] = ex + v0 + v1;
  if (base + 3 < n) dst[base + 3] = ex + v0 + v1 + v2;
  if (t == 255) part[blockIdx.x] = sh[255];
}

__global__ void scan2(int* __restrict__ part, int m) {
  __shared__ int sh[256];
  int t = threadIdx.x;
  int carry = 0;
  for (int base = 0; base < m; base += 256) {
    int v = (base + t < m) ? part[base + t] : 0;
    sh[t] = v;
    __syncthreads();
    for (int off = 1; off < 256; off <<= 1) {
      int y = (t >= off) ? sh[t - off] : 0;
      __syncthreads();
      if (t >= off) sh[t] += y;
      __syncthreads();
    }
    if (base + t < m) part[base + t] = carry + sh[t] - v;
    int tot = sh[255];
    __syncthreads();
    carry += tot;
  }
}

__global__ void scan3(int* __restrict__ dst, const int* __restrict__ part, int n) {
  int i = blockIdx.x * 256 + threadIdx.x;
  if (i < n) dst[i] += part[i >> 10];
}

__global__ void copy2(const int* __restrict__ a, int* __restrict__ b,
                      const int* __restrict__ c, int* __restrict__ d, int n) {
  int i = blockIdx.x * 256 + threadIdx.x;
  if (i < n) { b[i] = a[i]; d[i] = c[i]; }
}

__global__ void pos_k(const int* __restrict__ selfI, const int* __restrict__ parI,
                      int* curP, int* curC, int* posP, int* posC, int E) {
  int e = blockIdx.x * 256 + threadIdx.x;
  if (e < E) {
    posP[e] = atomicAdd(&curP[selfI[e]], 1);
    posC[e] = atomicAdd(&curC[parI[e]], 1);
  }
}

// ---- MLP_V: hidden = relu(relu(x@W1+b1)@W2+b2), K=128 -> 256 -> 128
__global__ __launch_bounds__(256) void v_kernel(
    const float* __restrict__ x, const unsigned short* __restrict__ W1t,
    const unsigned short* __restrict__ W2t, const float* __restrict__ b1,
    const float* __restrict__ b2, float* __restrict__ hidden, int n) {
  __shared__ __align__(16) unsigned short A[64 * 136];
  __shared__ __align__(16) unsigned short O1[64 * 264];
  int t = threadIdx.x;
  int w = t >> 6, lane = t & 63, ln = lane & 15, quad = lane >> 4, qo = quad * 8;
  long tile0 = (long)blockIdx.x * 64;
  int rl = t >> 2, part = t & 3;
  long gr = tile0 + rl;
  const float* src = x + (size_t)(gr < n ? gr : 0) * DD + part * 32;
  unsigned short* arow = A + rl * 136 + part * 32;
#pragma unroll
  for (int i = 0; i < 8; ++i) {
    float4 v = *(const float4*)(src + i * 4);
    *(ushort4*)(arow + i * 4) = make_ushort4(f2bf(v.x), f2bf(v.y), f2bf(v.z), f2bf(v.w));
  }
  const unsigned short* aRow = A + (w * 16 + ln) * 136;
  f32x4 zero4 = {0.f, 0.f, 0.f, 0.f};
  f32x4 acc1[16];
#pragma unroll
  for (int nt = 0; nt < 16; ++nt) acc1[nt] = zero4;
#pragma unroll
  for (int kt = 0; kt < 4; ++kt) {
    short8 a = *(const short8*)(aRow + kt * 32 + qo);
#pragma unroll
    for (int nt = 0; nt < 16; ++nt) {
      short8 b = *(const short8*)(W1t + (size_t)(nt * 16 + ln) * 128 + kt * 32 + qo);
      acc1[nt] = mfma16(a, b, acc1[nt]);
    }
  }
#pragma unroll
  for (int nt = 0; nt < 16; ++nt) {
    float bb = b1[nt * 16 + ln];
#pragma unroll
    for (int r = 0; r < 4; ++r)
      O1[(w * 16 + quad * 4 + r) * 264 + nt * 16 + ln] = f2bf(fmaxf(acc1[nt][r] + bb, 0.f));
  }
  const unsigned short* oRow = O1 + (w * 16 + ln) * 264;
  f32x4 acc2[8];
#pragma unroll
  for (int nt = 0; nt < 8; ++nt) acc2[nt] = zero4;
#pragma unroll
  for (int kt = 0; kt < 8; ++kt) {
    short8 a = *(const short8*)(oRow + kt * 32 + qo);
#pragma unroll
    for (int nt = 0; nt < 8; ++nt) {
      short8 b = *(const short8*)(W2t + (size_t)(nt * 16 + ln) * 256 + kt * 32 + qo);
      acc2[nt] = mfma16(a, b, acc2[nt]);
    }
  }
#pragma unroll
  for (int nt = 0; nt < 8; ++nt) {
    float bb = b2[nt * 16 + ln];
#pragma unroll
    for (int r = 0; r < 4; ++r) {
      long gr2 = tile0 + w * 16 + quad * 4 + r;
      if (gr2 < n) hidden[gr2 * DD + nt * 16 + ln] = fmaxf(acc2[nt][r] + bb, 0.f);
    }
  }
}

// ---- cooperative edge kernel: 512 thr / 8 waves, M=64 edges, waves split N-dim.
// Each weight byte read once per block (was 4x). P and C share the A-tile.
__global__ __launch_bounds__(512, 4) void edge_kernel(
    const float* __restrict__ hidden, const int* __restrict__ selfI, const int* __restrict__ parI,
    const int* __restrict__ posP, const int* __restrict__ posC,
    const unsigned short* __restrict__ Pw1t, const unsigned short* __restrict__ Pw2t,
    const unsigned short* __restrict__ Cw1t, const unsigned short* __restrict__ Cw2t,
    const float* __restrict__ b1P, const float* __restrict__ b1C,
    const float* __restrict__ b2P, const float* __restrict__ b2C,
    unsigned short* __restrict__ SpE, unsigned short* __restrict__ ScE, int E) {
  __shared__ __align__(16) unsigned short A[64 * 264];   // [hs|hp] bf16 tile
  __shared__ __align__(16) unsigned short O1[64 * 264];  // layer-1 out / repack buf
  int t = threadIdx.x;
  int w = t >> 6, lane = t & 63, ln = lane & 15, quad = lane >> 4, qo = quad * 8;
  long tile0 = (long)blockIdx.x * 64;
  // stage: 8 thr/row, 32 cols each; parts 0-3 = hs, 4-7 = hp
  int rl = t >> 3, part = t & 7;
  long ge = tile0 + rl;
  bool vrow = ge < E;
  int si = vrow ? selfI[ge] : 0;
  int pi = vrow ? parI[ge] : 0;
  const float* src = (part < 4) ? (hidden + (size_t)si * DD + part * 32)
                                : (hidden + (size_t)pi * DD + (part - 4) * 32);
  unsigned short* dstA = A + rl * 264 + part * 32;
#pragma unroll
  for (int i = 0; i < 8; ++i) {
    float4 v = *(const float4*)(src + i * 4);
    *(ushort4*)(dstA + i * 4) = make_ushort4(f2bf(v.x), f2bf(v.y), f2bf(v.z), f2bf(v.w));
  }
  __syncthreads();

  for (int mlp = 0; mlp < 2; ++mlp) {
    const unsigned short* W1t = mlp ? Cw1t : Pw1t;
    const unsigned short* W2t = mlp ? Cw2t : Pw2t;
    const float* b1 = mlp ? b1C : b1P;
    const float* b2 = mlp ? b2C : b2P;
    unsigned short* Sout = mlp ? ScE : SpE;
    const int* pos = mlp ? posC : posP;
    // layer 1: wave w -> cols [w*32, w*32+32)
    f32x4 acc[4][2];
#pragma unroll
    for (int m = 0; m < 4; ++m) {
      acc[m][0] = {0.f, 0.f, 0.f, 0.f}; acc[m][1] = {0.f, 0.f, 0.f, 0.f};
    }
#pragma unroll
    for (int kt = 0; kt < 8; ++kt) {
      short8 a[4];
#pragma unroll
      for (int m = 0; m < 4; ++m)
        a[m] = *(const short8*)(A + (m * 16 + ln) * 264 + kt * 32 + qo);
#pragma unroll
      for (int nn = 0; nn < 2; ++nn) {
        short8 b = *(const short8*)(W1t + (size_t)(w * 32 + nn * 16 + ln) * 256 + kt * 32 + qo);
#pragma unroll
        for (int m = 0; m < 4; ++m) acc[m][nn] = mfma16(a[m], b, acc[m][nn]);
      }
    }
#pragma unroll
    for (int nn = 0; nn < 2; ++nn) {
      int col = w * 32 + nn * 16 + ln;
      float bb = b1[col];
#pragma unroll
      for (int m = 0; m < 4; ++m)
#pragma unroll
        for (int r = 0; r < 4; ++r)
          O1[(m * 16 + quad * 4 + r) * 264 + col] = f2bf(fmaxf(acc[m][nn][r] + bb, 0.f));
    }
    __syncthreads();
    // layer 2: wave w -> cols [w*16, w*16+16)
    f32x4 acc2[4];
#pragma unroll
    for (int m = 0; m < 4; ++m) acc2[m] = {0.f, 0.f, 0.f, 0.f};
#pragma unroll
    for (int kt = 0; kt < 8; ++kt) {
      short8 b = *(const short8*)(W2t + (size_t)(w * 16 + ln) * 256 + kt * 32 + qo);
#pragma unroll
      for (int m = 0; m < 4; ++m) {
        short8 a = *(const short8*)(O1 + (m * 16 + ln) * 264 + kt * 32 + qo);
        acc2[m] = mfma16(a, b, acc2[m]);
      }
    }
    __syncthreads();  // O1 reads done -> safe to overwrite with repack
    {
      int col = w * 16 + ln;
      float bb = b2[col];
#pragma unroll
      for (int m = 0; m < 4; ++m)
#pragma unroll
        for (int r = 0; r < 4; ++r)
          O1[(m * 16 + quad * 4 + r) * 264 + col] = f2bf(fmaxf(acc2[m][r] + bb, 0.f));
    }
    __syncthreads();
    // scatter rows to CSR positions: 8 thr/row x 16 cols (256B/row contiguous)
    if (vrow) {
      int dpos = pos[ge];
      const unsigned short* srow = O1 + rl * 264 + part * 16;
      ushort4* dst = (ushort4*)(Sout + (size_t)dpos * DD + part * 16);
#pragma unroll
      for (int i = 0; i < 4; ++i) dst[i] = *(const ushort4*)(srow + i * 4);
    }
    __syncthreads();  // store LDS-reads done before next mlp overwrites O1
  }
}

// ---- cooperative node kernel: CSR gather-mean (contiguous rows, no chase),
// build [h|S_p|S_c], MLP_A (K=384), residual add. 512 thr, O1 overlaid on A.
__global__ __launch_bounds__(512, 4) void node_kernel(
    float* __restrict__ hidden,
    const unsigned short* __restrict__ SpE, const unsigned short* __restrict__ ScE,
    const int* __restrict__ offP, const int* __restrict__ degP,
    const int* __restrict__ offC, const int* __restrict__ degC,
    const float* __restrict__ rootM, const float* __restrict__ leafM,
    const float* __restrict__ startT, const float* __restrict__ endT,
    const unsigned short* __restrict__ W1t, const unsigned short* __restrict__ W2t,
    const float* __restrict__ b1, const float* __restrict__ b2, int n) {
  __shared__ __align__(16) unsigned short A[64 * 392];
  int t = threadIdx.x;
  int w = t >> 6, lane = t & 63, ln = lane & 15, quad = lane >> 4, qo = quad * 8;
  long tile0 = (long)blockIdx.x * 64;
  int rl = t >> 3, part = t & 7;
  int c0 = part * 16;
  long gr = tile0 + rl;
  long g = (gr < n) ? gr : 0;
  unsigned short* arow = A + rl * 392;
  {  // h cols
    const float* hrow = hidden + (size_t)g * DD + c0;
#pragma unroll
    for (int i = 0; i < 4; ++i) {
      float4 h = *(const float4*)(hrow + i * 4);
      *(ushort4*)(arow + c0 + i * 4) = make_ushort4(f2bf(h.x), f2bf(h.y), f2bf(h.z), f2bf(h.w));
    }
  }
  {  // S_p mean: contiguous CSR rows
    int off = offP[g], dg = degP[g];
    float s[16];
#pragma unroll
    for (int i = 0; i < 16; ++i) s[i] = 0.f;
    for (int j = 0; j < dg; ++j) {
      const unsigned short* rr = SpE + (size_t)(off + j) * DD + c0;
#pragma unroll
      for (int i = 0; i < 4; ++i) {
        ushort4 u = *(const ushort4*)(rr + i * 4);
        s[i * 4 + 0] += bf2f(u.x); s[i * 4 + 1] += bf2f(u.y);
        s[i * 4 + 2] += bf2f(u.z); s[i * 4 + 3] += bf2f(u.w);
      }
    }
    float ip = 1.f / fmaxf((float)dg, 1.f);
    float rm = rootM[g];
#pragma unroll
    for (int i = 0; i < 4; ++i) {
      float4 st = *(const float4*)(startT + c0 + i * 4);
      *(ushort4*)(arow + 128 + c0 + i * 4) = make_ushort4(
          f2bf(s[i * 4 + 0] * ip + rm * st.x), f2bf(s[i * 4 + 1] * ip + rm * st.y),
          f2bf(s[i * 4 + 2] * ip + rm * st.z), f2bf(s[i * 4 + 3] * ip + rm * st.w));
    }
  }
  {  // S_c mean
    int off = offC[g], dg = degC[g];
    float s[16];
#pragma unroll
    for (int i = 0; i < 16; ++i) s[i] = 0.f;
    for (int j = 0; j < dg; ++j) {
      const unsigned short* rr = ScE + (size_t)(off + j) * DD + c0;
#pragma unroll
      for (int i = 0; i < 4; ++i) {
        ushort4 u = *(const ushort4*)(rr + i * 4);
        s[i * 4 + 0] += bf2f(u.x); s[i * 4 + 1] += bf2f(u.y);
        s[i * 4 + 2] += bf2f(u.z); s[i * 4 + 3] += bf2f(u.w);
      }
    }
    float ic = 1.f / fmaxf((float)dg, 1.f);
    float lm = leafM[g];
#pragma unroll
    for (int i = 0; i < 4; ++i) {
      float4 et = *(const float4*)(endT + c0 + i * 4);
      *(ushort4*)(arow + 256 + c0 + i * 4) = make_ushort4(
          f2bf(s[i * 4 + 0] * ic + lm * et.x), f2bf(s[i * 4 + 1] * ic + lm * et.y),
          f2bf(s[i * 4 + 2] * ic + lm * et.z), f2bf(s[i * 4 + 3] * ic + lm * et.w));
    }
  }
  __syncthreads();
  // layer 1 (K=384): wave w -> cols [w*32, w*32+32)
  f32x4 acc[4][2];
#pragma unroll
  for (int m = 0; m < 4; ++m) {
    acc[m][0] = {0.f, 0.f, 0.f, 0.f}; acc[m][1] = {0.f, 0.f, 0.f, 0.f};
  }
#pragma unroll
  for (int kt = 0; kt < 12; ++kt) {
    short8 a[4];
#pragma unroll
    for (int m = 0; m < 4; ++m)
      a[m] = *(const short8*)(A + (m * 16 + ln) * 392 + kt * 32 + qo);
#pragma unroll
    for (int nn = 0; nn < 2; ++nn) {
      short8 b = *(const short8*)(W1t + (size_t)(w * 32 + nn * 16 + ln) * 384 + kt * 32 + qo);
#pragma unroll
      for (int m = 0; m < 4; ++m) acc[m][nn] = mfma16(a[m], b, acc[m][nn]);
    }
  }
  __syncthreads();  // all A reads done -> overlay O1 into A storage
#pragma unroll
  for (int nn = 0; nn < 2; ++nn) {
    int col = w * 32 + nn * 16 + ln;
    float bb = b1[col];
#pragma unroll
    for (int m = 0; m < 4; ++m)
#pragma unroll
      for (int r = 0; r < 4; ++r)
        A[(m * 16 + quad * 4 + r) * 392 + col] = f2bf(fmaxf(acc[m][nn][r] + bb, 0.f));
  }
  __syncthreads();
  // layer 2 (K=256): wave w -> cols [w*16, w*16+16)
  f32x4 acc2[4];
#pragma unroll
  for (int m = 0; m < 4; ++m) acc2[m] = {0.f, 0.f, 0.f, 0.f};
#pragma unroll
  for (int kt = 0; kt < 8; ++kt) {
    short8 b = *(const short8*)(W2t + (size_t)(w * 16 + ln) * 256 + kt * 32 + qo);
#pragma unroll
    for (int m = 0; m < 4; ++m) {
      short8 a = *(const short8*)(A + (m * 16 + ln) * 392 + kt * 32 + qo);
      acc2[m] = mfma16(a, b, acc2[m]);
    }
  }
  __syncthreads();  // O1 reads done -> overlay fp32 repack (keeps residual in fp32)
  {
    int col = w * 16 + ln;
    float bb = b2[col];
#pragma unroll
    for (int m = 0; m < 4; ++m)
#pragma unroll
      for (int r = 0; r < 4; ++r)
        ((float*)(A + (size_t)(m * 16 + quad * 4 + r) * 392))[col] =
            fmaxf(acc2[m][r] + bb, 0.f);
  }
  __syncthreads();
  if (gr < n) {
    const float* F = (const float*)(A + (size_t)rl * 392);
    float* hrow = hidden + (size_t)gr * DD + c0;
#pragma unroll
    for (int i = 0; i < 4; ++i) {
      float4 v = *(const float4*)(F + c0 + i * 4);
      float4 h = *(const float4*)(hrow + i * 4);
      h.x += v.x; h.y += v.y; h.z += v.z; h.w += v.w;
      *(float4*)(hrow + i * 4) = h;
    }
  }
}

extern "C" void kernel_launch(void* const* d_in, const int* in_sizes, int n_in,
                              void* d_out, int out_size, void* d_ws, size_t ws_size,
                              hipStream_t stream) {
  const float* batch  = (const float*)d_in[0];
  const int*   selfI  = (const int*)d_in[1];
  const int*   parI   = (const int*)d_in[2];
  const float* rootM  = (const float*)d_in[3];
  const float* leafM  = (const float*)d_in[4];
  const float* startT = (const float*)d_in[5];
  const float* endT   = (const float*)d_in[6];
  const float* Vw1 = (const float*)d_in[7],  *Vb1 = (const float*)d_in[8];
  const float* Vw2 = (const float*)d_in[9],  *Vb2 = (const float*)d_in[10];
  const float* Ew1 = (const float*)d_in[11], *Eb1 = (const float*)d_in[12];
  const float* Ew2 = (const float*)d_in[13], *Eb2 = (const float*)d_in[14];
  const float* Pw1 = (const float*)d_in[15], *Pb1 = (const float*)d_in[16];
  const float* Pw2 = (const float*)d_in[17], *Pb2 = (const float*)d_in[18];
  const float* Cw1 = (const float*)d_in[19], *Cb1 = (const float*)d_in[20];
  const float* Cw2 = (const float*)d_in[21], *Cb2 = (const float*)d_in[22];
  const float* Aw1 = (const float*)d_in[23], *Ab1 = (const float*)d_in[24];
  const float* Aw2 = (const float*)d_in[25], *Ab2 = (const float*)d_in[26];

  const int N = in_sizes[3];
  const int E = in_sizes[1];
  float* out = (float*)d_out;

  char* p = (char*)d_ws;
  auto nxt = [&](size_t sz) { char* r = p; p += (sz + 255) & ~(size_t)255; return r; };
  unsigned short* SpE = (unsigned short*)nxt((size_t)E * DD * 2);
  unsigned short* ScE = (unsigned short*)nxt((size_t)E * DD * 2);
  int* degP = (int*)nxt((size_t)N * 4);
  int* degC = (int*)nxt((size_t)N * 4);
  int* offP = (int*)nxt((size_t)N * 4);
  int* offC = (int*)nxt((size_t)N * 4);
  int* curP = (int*)nxt((size_t)N * 4);
  int* curC = (int*)nxt((size_t)N * 4);
  int* posP = (int*)nxt((size_t)E * 4);
  int* posC = (int*)nxt((size_t)E * 4);
  int* partA = (int*)nxt(4096);
  int* partB = (int*)nxt(4096);
  unsigned short* Vw1t = (unsigned short*)nxt((size_t)128 * 256 * 2);
  unsigned short* Vw2t = (unsigned short*)nxt((size_t)256 * 128 * 2);
  unsigned short* Pw1t = (unsigned short*)nxt((size_t)256 * 256 * 2);
  unsigned short* Pw2t = (unsigned short*)nxt((size_t)256 * 128 * 2);
  unsigned short* Cw1t = (unsigned short*)nxt((size_t)256 * 256 * 2);
  unsigned short* Cw2t = (unsigned short*)nxt((size_t)256 * 128 * 2);
  unsigned short* Aw1t = (unsigned short*)nxt((size_t)384 * 256 * 2);
  unsigned short* Aw2t = (unsigned short*)nxt((size_t)256 * 128 * 2);
  float* b1P = (float*)nxt(256 * 4);
  float* b1C = (float*)nxt(256 * 4);
  // total ws usage ~137 MB (proven-safe envelope)

  hipMemsetAsync(degP, 0, (size_t)N * 4, stream);
  hipMemsetAsync(degC, 0, (size_t)N * 4, stream);

  auto blk = [](int total) { return dim3((total + 255) / 256); };
  wconv<<<blk(128 * 256), 256, 0, stream>>>(Vw1, Vw1t, 128, 256, 0);
  wconv<<<blk(256 * 128), 256, 0, stream>>>(Vw2, Vw2t, 256, 128, 0);
  wconv<<<blk(256 * 256), 256, 0, stream>>>(Pw1, Pw1t, 256, 256, 128);  // half-swap
  wconv<<<blk(256 * 128), 256, 0, stream>>>(Pw2, Pw2t, 256, 128, 0);
  wconv<<<blk(256 * 256), 256, 0, stream>>>(Cw1, Cw1t, 256, 256, 0);
  wconv<<<blk(256 * 128), 256, 0, stream>>>(Cw2, Cw2t, 256, 128, 0);
  wconv<<<blk(384 * 256), 256, 0, stream>>>(Aw1, Aw1t, 384, 256, 0);
  wconv<<<blk(256 * 128), 256, 0, stream>>>(Aw2, Aw2t, 256, 128, 0);

  prep_bias<<<1, 256, 0, stream>>>(Ew1, Eb1, Ew2, Eb2, Pw1, Pb1, Cw1, Cb1, b1P, b1C);
  count_k<<<blk(E), 256, 0, stream>>>(selfI, parI, degP, degC, E);

  int NB = (N + 1023) / 1024;
  scan1<<<NB, 256, 0, stream>>>(degP, offP, partA, N);
  scan1<<<NB, 256, 0, stream>>>(degC, offC, partB, N);
  scan2<<<1, 256, 0, stream>>>(partA, NB);
  scan2<<<1, 256, 0, stream>>>(partB, NB);
  scan3<<<blk(N), 256, 0, stream>>>(offP, partA, N);
  scan3<<<blk(N), 256, 0, stream>>>(offC, partB, N);
  copy2<<<blk(N), 256, 0, stream>>>(offP, curP, offC, curC, N);
  pos_k<<<blk(E), 256, 0, stream>>>(selfI, parI, curP, curC, posP, posC, E);

  dim3 gN((N + 63) / 64), gE((E + 63) / 64);
  v_kernel<<<gN, 256, 0, stream>>>(batch, Vw1t, Vw2t, Vb1, Vb2, out, N);

  for (int hop = 0; hop < 3; ++hop) {
    edge_kernel<<<gE, 512, 0, stream>>>(out, selfI, parI, posP, posC,
                                        Pw1t, Pw2t, Cw1t, Cw2t, b1P, b1C, Pb2, Cb2,
                                        SpE, ScE, E);
    node_kernel<<<gN, 512, 0, stream>>>(out, SpE, ScE, offP, degP, offC, degC,
                                        rootM, leafM, startT, endT,
                                        Aw1t, Aw2t, Ab1, Ab2, N);
  }
}

// Round 4
// 1831.183 us; speedup vs baseline: 2.9983x; 1.0670x over previous
//
#include <hip/hip_runtime.h>

typedef __attribute__((ext_vector_type(8))) short short8;
typedef __attribute__((ext_vector_type(4))) float f32x4;

#define DD 128
#define HH 256

__device__ __forceinline__ unsigned short f2bf(float f) {
  unsigned int u = __float_as_uint(f);
  u += 0x7fffu + ((u >> 16) & 1u);
  return (unsigned short)(u >> 16);
}
__device__ __forceinline__ float bf2f(unsigned short s) {
  return __uint_as_float(((unsigned int)s) << 16);
}
__device__ __forceinline__ f32x4 mfma16(short8 a, short8 b, f32x4 c) {
  return __builtin_amdgcn_mfma_f32_16x16x32_bf16(a, b, c, 0, 0, 0);
}

// ---- weight convert: dst[n][k] = bf16(src[(k+kswap)%K][n]), src row stride = Nout
__global__ void wconv(const float* __restrict__ src, unsigned short* __restrict__ dst,
                      int K, int Nout, int kswap) {
  int id = blockIdx.x * 256 + threadIdx.x;
  if (id >= K * Nout) return;
  int n = id / K, k = id - n * K;
  int ks = k + kswap; if (ks >= K) ks -= K;
  dst[n * K + k] = f2bf(src[(size_t)ks * Nout + n]);
}

// ---- edge vectors + fold edge constants into layer-1 biases (1 block, 256 thr)
__global__ void prep_bias(const float* __restrict__ Ew1, const float* __restrict__ Eb1,
                          const float* __restrict__ Ew2, const float* __restrict__ Eb2,
                          const float* __restrict__ Pw1, const float* __restrict__ Pb1,
                          const float* __restrict__ Cw1, const float* __restrict__ Cb1,
                          float* __restrict__ b1P, float* __restrict__ b1C) {
  __shared__ float h1[HH], h0[HH], ein[DD], eout[DD];
  int t = threadIdx.x;
  h1[t] = fmaxf(Ew1[t] + Eb1[t], 0.f);
  h0[t] = fmaxf(Eb1[t], 0.f);
  __syncthreads();
  if (t < DD) {
    float s1 = Eb2[t], s0 = Eb2[t];
    for (int j = 0; j < HH; ++j) { s1 += h1[j] * Ew2[j * DD + t]; s0 += h0[j] * Ew2[j * DD + t]; }
    ein[t]  = fmaxf(s1, 0.f);
    eout[t] = fmaxf(s0, 0.f);
  }
  __syncthreads();
  float bp = Pb1[t], bc = Cb1[t];
  for (int d = 0; d < DD; ++d) {
    bp += eout[d] * Pw1[(size_t)(256 + d) * HH + t];
    bc += ein[d]  * Cw1[(size_t)(256 + d) * HH + t];
  }
  b1P[t] = bp; b1C[t] = bc;
}

// ---- CSR build: degree count, 3-kernel exclusive scan, per-edge position
__global__ void count_k(const int* __restrict__ selfI, const int* __restrict__ parI,
                        int* degP, int* degC, int E) {
  int id = blockIdx.x * 256 + threadIdx.x;
  if (id < E) { atomicAdd(&degP[selfI[id]], 1); atomicAdd(&degC[parI[id]], 1); }
}

__global__ void scan1(const int* __restrict__ src, int* __restrict__ dst,
                      int* __restrict__ part, int n) {
  __shared__ int sh[256];
  int t = threadIdx.x;
  int base = blockIdx.x * 1024 + t * 4;
  int v0 = base + 0 < n ? src[base + 0] : 0;
  int v1 = base + 1 < n ? src[base + 1] : 0;
  int v2 = base + 2 < n ? src[base + 2] : 0;
  int v3 = base + 3 < n ? src[base + 3] : 0;
  int tsum = v0 + v1 + v2 + v3;
  sh[t] = tsum;
  __syncthreads();
  for (int off = 1; off < 256; off <<= 1) {
    int y = (t >= off) ? sh[t - off] : 0;
    __syncthreads();
    if (t >= off) sh[t] += y;
    __syncthreads();
  }
  int ex = sh[t] - tsum;
  if (base + 0 < n) dst[base + 0] = ex;
  if (base + 1 < n) dst[base + 1] = ex + v0;
  if (base + 2 < n) dst[base + 2] = ex + v0 + v1;
  if (base + 3 < n) dst[base + 3] = ex + v0 + v1 + v2;
  if (t == 255) part[blockIdx.x] = sh[255];
}

__global__ void scan2(int* __restrict__ part, int m) {
  __shared__ int sh[256];
  int t = threadIdx.x;
  int carry = 0;
  for (int base = 0; base < m; base += 256) {
    int v = (base + t < m) ? part[base + t] : 0;
    sh[t] = v;
    __syncthreads();
    for (int off = 1; off < 256; off <<= 1) {
      int y = (t >= off) ? sh[t - off] : 0;
      __syncthreads();
      if (t >= off) sh[t] += y;
      __syncthreads();
    }
    if (base + t < m) part[base + t] = carry + sh[t] - v;
    int tot = sh[255];
    __syncthreads();
    carry += tot;
  }
}

__global__ void scan3(int* __restrict__ dst, const int* __restrict__ part, int n) {
  int i = blockIdx.x * 256 + threadIdx.x;
  if (i < n) dst[i] += part[i >> 10];
}

__global__ void copy2(const int* __restrict__ a, int* __restrict__ b,
                      const int* __restrict__ c, int* __restrict__ d, int n) {
  int i = blockIdx.x * 256 + threadIdx.x;
  if (i < n) { b[i] = a[i]; d[i] = c[i]; }
}

__global__ void pos_k(const int* __restrict__ selfI, const int* __restrict__ parI,
                      int* curP, int* curC, int* posP, int* posC, int E) {
  int e = blockIdx.x * 256 + threadIdx.x;
  if (e < E) {
    posP[e] = atomicAdd(&curP[selfI[e]], 1);
    posC[e] = atomicAdd(&curC[parI[e]], 1);
  }
}

// ---- cooperative MLP_V: 512 thr / 8 waves, waves split N-dim.
// K=128 -> 256 -> 128. Weights read once per block (was once per wave).
__global__ __launch_bounds__(512, 4) void v_kernel(
    const float* __restrict__ x, const unsigned short* __restrict__ W1t,
    const unsigned short* __restrict__ W2t, const float* __restrict__ b1,
    const float* __restrict__ b2, float* __restrict__ hidden, int n) {
  __shared__ __align__(16) unsigned short A[64 * 136];
  __shared__ __align__(16) unsigned short O1[64 * 264];
  int t = threadIdx.x;
  int w = t >> 6, lane = t & 63, ln = lane & 15, quad = lane >> 4, qo = quad * 8;
  long tile0 = (long)blockIdx.x * 64;
  int rl = t >> 3, part = t & 7;
  int c0 = part * 16;
  long gr = tile0 + rl;
  const float* src = x + (size_t)(gr < n ? gr : 0) * DD + c0;
  unsigned short* arow = A + rl * 136 + c0;
#pragma unroll
  for (int i = 0; i < 4; ++i) {
    float4 v = *(const float4*)(src + i * 4);
    *(ushort4*)(arow + i * 4) = make_ushort4(f2bf(v.x), f2bf(v.y), f2bf(v.z), f2bf(v.w));
  }
  __syncthreads();
  // layer 1 (K=128): wave w -> cols [w*32, w*32+32)
  f32x4 acc[4][2];
#pragma unroll
  for (int m = 0; m < 4; ++m) {
    acc[m][0] = {0.f, 0.f, 0.f, 0.f}; acc[m][1] = {0.f, 0.f, 0.f, 0.f};
  }
#pragma unroll
  for (int kt = 0; kt < 4; ++kt) {
    short8 a[4];
#pragma unroll
    for (int m = 0; m < 4; ++m)
      a[m] = *(const short8*)(A + (m * 16 + ln) * 136 + kt * 32 + qo);
#pragma unroll
    for (int nn = 0; nn < 2; ++nn) {
      short8 b = *(const short8*)(W1t + (size_t)(w * 32 + nn * 16 + ln) * 128 + kt * 32 + qo);
#pragma unroll
      for (int m = 0; m < 4; ++m) acc[m][nn] = mfma16(a[m], b, acc[m][nn]);
    }
  }
#pragma unroll
  for (int nn = 0; nn < 2; ++nn) {
    int col = w * 32 + nn * 16 + ln;
    float bb = b1[col];
#pragma unroll
    for (int m = 0; m < 4; ++m)
#pragma unroll
      for (int r = 0; r < 4; ++r)
        O1[(m * 16 + quad * 4 + r) * 264 + col] = f2bf(fmaxf(acc[m][nn][r] + bb, 0.f));
  }
  __syncthreads();
  // layer 2 (K=256): wave w -> cols [w*16, w*16+16)
  f32x4 acc2[4];
#pragma unroll
  for (int m = 0; m < 4; ++m) acc2[m] = {0.f, 0.f, 0.f, 0.f};
#pragma unroll
  for (int kt = 0; kt < 8; ++kt) {
    short8 b = *(const short8*)(W2t + (size_t)(w * 16 + ln) * 256 + kt * 32 + qo);
#pragma unroll
    for (int m = 0; m < 4; ++m) {
      short8 a = *(const short8*)(O1 + (m * 16 + ln) * 264 + kt * 32 + qo);
      acc2[m] = mfma16(a, b, acc2[m]);
    }
  }
  {
    int col = w * 16 + ln;
    float bb = b2[col];
#pragma unroll
    for (int m = 0; m < 4; ++m)
#pragma unroll
      for (int r = 0; r < 4; ++r) {
        long gr2 = tile0 + m * 16 + quad * 4 + r;
        if (gr2 < n) hidden[gr2 * DD + col] = fmaxf(acc2[m][r] + bb, 0.f);
      }
  }
}

// ---- cooperative edge kernel: 512 thr / 8 waves, M=64 edges, waves split N-dim.
// P+C layer-1 FUSED over one A-tile read (accC stays in regs through P phase).
__global__ __launch_bounds__(512, 4) void edge_kernel(
    const float* __restrict__ hidden, const int* __restrict__ selfI, const int* __restrict__ parI,
    const int* __restrict__ posP, const int* __restrict__ posC,
    const unsigned short* __restrict__ Pw1t, const unsigned short* __restrict__ Pw2t,
    const unsigned short* __restrict__ Cw1t, const unsigned short* __restrict__ Cw2t,
    const float* __restrict__ b1P, const float* __restrict__ b1C,
    const float* __restrict__ b2P, const float* __restrict__ b2C,
    unsigned short* __restrict__ SpE, unsigned short* __restrict__ ScE, int E) {
  __shared__ __align__(16) unsigned short A[64 * 264];   // [hs|hp] bf16 tile
  __shared__ __align__(16) unsigned short O1[64 * 264];  // layer-1 out / repack buf
  int t = threadIdx.x;
  int w = t >> 6, lane = t & 63, ln = lane & 15, quad = lane >> 4, qo = quad * 8;
  long tile0 = (long)blockIdx.x * 64;
  int rl = t >> 3, part = t & 7;
  long ge = tile0 + rl;
  bool vrow = ge < E;
  int si = vrow ? selfI[ge] : 0;
  int pi = vrow ? parI[ge] : 0;
  const float* src = (part < 4) ? (hidden + (size_t)si * DD + part * 32)
                                : (hidden + (size_t)pi * DD + (part - 4) * 32);
  unsigned short* dstA = A + rl * 264 + part * 32;
#pragma unroll
  for (int i = 0; i < 8; ++i) {
    float4 v = *(const float4*)(src + i * 4);
    *(ushort4*)(dstA + i * 4) = make_ushort4(f2bf(v.x), f2bf(v.y), f2bf(v.z), f2bf(v.w));
  }
  __syncthreads();

  // fused layer 1 for P and C: one a[4] read feeds 16 MFMAs
  f32x4 accP[4][2], accC[4][2];
#pragma unroll
  for (int m = 0; m < 4; ++m) {
    accP[m][0] = {0.f, 0.f, 0.f, 0.f}; accP[m][1] = {0.f, 0.f, 0.f, 0.f};
    accC[m][0] = {0.f, 0.f, 0.f, 0.f}; accC[m][1] = {0.f, 0.f, 0.f, 0.f};
  }
#pragma unroll
  for (int kt = 0; kt < 8; ++kt) {
    short8 a[4];
#pragma unroll
    for (int m = 0; m < 4; ++m)
      a[m] = *(const short8*)(A + (m * 16 + ln) * 264 + kt * 32 + qo);
#pragma unroll
    for (int nn = 0; nn < 2; ++nn) {
      short8 bp = *(const short8*)(Pw1t + (size_t)(w * 32 + nn * 16 + ln) * 256 + kt * 32 + qo);
      short8 bc = *(const short8*)(Cw1t + (size_t)(w * 32 + nn * 16 + ln) * 256 + kt * 32 + qo);
#pragma unroll
      for (int m = 0; m < 4; ++m) {
        accP[m][nn] = mfma16(a[m], bp, accP[m][nn]);
        accC[m][nn] = mfma16(a[m], bc, accC[m][nn]);
      }
    }
  }
  __syncthreads();  // A reads done (A no longer needed)

#pragma unroll
  for (int mlp = 0; mlp < 2; ++mlp) {
    const unsigned short* W2t = mlp ? Cw2t : Pw2t;
    const float* b1 = mlp ? b1C : b1P;
    const float* b2 = mlp ? b2C : b2P;
    unsigned short* Sout = mlp ? ScE : SpE;
    const int* pos = mlp ? posC : posP;
    // write O1 = relu(acc + b1)
#pragma unroll
    for (int nn = 0; nn < 2; ++nn) {
      int col = w * 32 + nn * 16 + ln;
      float bb = b1[col];
#pragma unroll
      for (int m = 0; m < 4; ++m)
#pragma unroll
        for (int r = 0; r < 4; ++r) {
          float v = mlp ? accC[m][nn][r] : accP[m][nn][r];
          O1[(m * 16 + quad * 4 + r) * 264 + col] = f2bf(fmaxf(v + bb, 0.f));
        }
    }
    __syncthreads();
    // layer 2: wave w -> cols [w*16, w*16+16)
    f32x4 acc2[4];
#pragma unroll
    for (int m = 0; m < 4; ++m) acc2[m] = {0.f, 0.f, 0.f, 0.f};
#pragma unroll
    for (int kt = 0; kt < 8; ++kt) {
      short8 b = *(const short8*)(W2t + (size_t)(w * 16 + ln) * 256 + kt * 32 + qo);
#pragma unroll
      for (int m = 0; m < 4; ++m) {
        short8 a = *(const short8*)(O1 + (m * 16 + ln) * 264 + kt * 32 + qo);
        acc2[m] = mfma16(a, b, acc2[m]);
      }
    }
    __syncthreads();  // O1 reads done -> safe to overwrite with repack
    {
      int col = w * 16 + ln;
      float bb = b2[col];
#pragma unroll
      for (int m = 0; m < 4; ++m)
#pragma unroll
        for (int r = 0; r < 4; ++r)
          O1[(m * 16 + quad * 4 + r) * 264 + col] = f2bf(fmaxf(acc2[m][r] + bb, 0.f));
    }
    __syncthreads();
    // scatter rows to CSR positions: 8 thr/row x 16 cols (256B/row contiguous)
    if (vrow) {
      int dpos = pos[ge];
      const unsigned short* srow = O1 + rl * 264 + part * 16;
      ushort4* dst = (ushort4*)(Sout + (size_t)dpos * DD + part * 16);
#pragma unroll
      for (int i = 0; i < 4; ++i) dst[i] = *(const ushort4*)(srow + i * 4);
    }
    __syncthreads();  // store LDS-reads done before next mlp overwrites O1
  }
}

// ---- cooperative node kernel: CSR gather-mean (contiguous rows, no chase),
// build [h|S_p|S_c], MLP_A (K=384), residual add. 512 thr, O1 overlaid on A.
__global__ __launch_bounds__(512, 4) void node_kernel(
    float* __restrict__ hidden,
    const unsigned short* __restrict__ SpE, const unsigned short* __restrict__ ScE,
    const int* __restrict__ offP, const int* __restrict__ degP,
    const int* __restrict__ offC, const int* __restrict__ degC,
    const float* __restrict__ rootM, const float* __restrict__ leafM,
    const float* __restrict__ startT, const float* __restrict__ endT,
    const unsigned short* __restrict__ W1t, const unsigned short* __restrict__ W2t,
    const float* __restrict__ b1, const float* __restrict__ b2, int n) {
  __shared__ __align__(16) unsigned short A[64 * 392];
  int t = threadIdx.x;
  int w = t >> 6, lane = t & 63, ln = lane & 15, quad = lane >> 4, qo = quad * 8;
  long tile0 = (long)blockIdx.x * 64;
  int rl = t >> 3, part = t & 7;
  int c0 = part * 16;
  long gr = tile0 + rl;
  long g = (gr < n) ? gr : 0;
  unsigned short* arow = A + rl * 392;
  {  // h cols
    const float* hrow = hidden + (size_t)g * DD + c0;
#pragma unroll
    for (int i = 0; i < 4; ++i) {
      float4 h = *(const float4*)(hrow + i * 4);
      *(ushort4*)(arow + c0 + i * 4) = make_ushort4(f2bf(h.x), f2bf(h.y), f2bf(h.z), f2bf(h.w));
    }
  }
  {  // S_p mean: contiguous CSR rows
    int off = offP[g], dg = degP[g];
    float s[16];
#pragma unroll
    for (int i = 0; i < 16; ++i) s[i] = 0.f;
    for (int j = 0; j < dg; ++j) {
      const unsigned short* rr = SpE + (size_t)(off + j) * DD + c0;
#pragma unroll
      for (int i = 0; i < 4; ++i) {
        ushort4 u = *(const ushort4*)(rr + i * 4);
        s[i * 4 + 0] += bf2f(u.x); s[i * 4 + 1] += bf2f(u.y);
        s[i * 4 + 2] += bf2f(u.z); s[i * 4 + 3] += bf2f(u.w);
      }
    }
    float ip = 1.f / fmaxf((float)dg, 1.f);
    float rm = rootM[g];
#pragma unroll
    for (int i = 0; i < 4; ++i) {
      float4 st = *(const float4*)(startT + c0 + i * 4);
      *(ushort4*)(arow + 128 + c0 + i * 4) = make_ushort4(
          f2bf(s[i * 4 + 0] * ip + rm * st.x), f2bf(s[i * 4 + 1] * ip + rm * st.y),
          f2bf(s[i * 4 + 2] * ip + rm * st.z), f2bf(s[i * 4 + 3] * ip + rm * st.w));
    }
  }
  {  // S_c mean
    int off = offC[g], dg = degC[g];
    float s[16];
#pragma unroll
    for (int i = 0; i < 16; ++i) s[i] = 0.f;
    for (int j = 0; j < dg; ++j) {
      const unsigned short* rr = ScE + (size_t)(off + j) * DD + c0;
#pragma unroll
      for (int i = 0; i < 4; ++i) {
        ushort4 u = *(const ushort4*)(rr + i * 4);
        s[i * 4 + 0] += bf2f(u.x); s[i * 4 + 1] += bf2f(u.y);
        s[i * 4 + 2] += bf2f(u.z); s[i * 4 + 3] += bf2f(u.w);
      }
    }
    float ic = 1.f / fmaxf((float)dg, 1.f);
    float lm = leafM[g];
#pragma unroll
    for (int i = 0; i < 4; ++i) {
      float4 et = *(const float4*)(endT + c0 + i * 4);
      *(ushort4*)(arow + 256 + c0 + i * 4) = make_ushort4(
          f2bf(s[i * 4 + 0] * ic + lm * et.x), f2bf(s[i * 4 + 1] * ic + lm * et.y),
          f2bf(s[i * 4 + 2] * ic + lm * et.z), f2bf(s[i * 4 + 3] * ic + lm * et.w));
    }
  }
  __syncthreads();
  // layer 1 (K=384): wave w -> cols [w*32, w*32+32)
  f32x4 acc[4][2];
#pragma unroll
  for (int m = 0; m < 4; ++m) {
    acc[m][0] = {0.f, 0.f, 0.f, 0.f}; acc[m][1] = {0.f, 0.f, 0.f, 0.f};
  }
#pragma unroll
  for (int kt = 0; kt < 12; ++kt) {
    short8 a[4];
#pragma unroll
    for (int m = 0; m < 4; ++m)
      a[m] = *(const short8*)(A + (m * 16 + ln) * 392 + kt * 32 + qo);
#pragma unroll
    for (int nn = 0; nn < 2; ++nn) {
      short8 b = *(const short8*)(W1t + (size_t)(w * 32 + nn * 16 + ln) * 384 + kt * 32 + qo);
#pragma unroll
      for (int m = 0; m < 4; ++m) acc[m][nn] = mfma16(a[m], b, acc[m][nn]);
    }
  }
  __syncthreads();  // all A reads done -> overlay O1 into A storage
#pragma unroll
  for (int nn = 0; nn < 2; ++nn) {
    int col = w * 32 + nn * 16 + ln;
    float bb = b1[col];
#pragma unroll
    for (int m = 0; m < 4; ++m)
#pragma unroll
      for (int r = 0; r < 4; ++r)
        A[(m * 16 + quad * 4 + r) * 392 + col] = f2bf(fmaxf(acc[m][nn][r] + bb, 0.f));
  }
  __syncthreads();
  // layer 2 (K=256): wave w -> cols [w*16, w*16+16)
  f32x4 acc2[4];
#pragma unroll
  for (int m = 0; m < 4; ++m) acc2[m] = {0.f, 0.f, 0.f, 0.f};
#pragma unroll
  for (int kt = 0; kt < 8; ++kt) {
    short8 b = *(const short8*)(W2t + (size_t)(w * 16 + ln) * 256 + kt * 32 + qo);
#pragma unroll
    for (int m = 0; m < 4; ++m) {
      short8 a = *(const short8*)(A + (m * 16 + ln) * 392 + kt * 32 + qo);
      acc2[m] = mfma16(a, b, acc2[m]);
    }
  }
  __syncthreads();  // O1 reads done -> overlay fp32 repack (keeps residual in fp32)
  {
    int col = w * 16 + ln;
    float bb = b2[col];
#pragma unroll
    for (int m = 0; m < 4; ++m)
#pragma unroll
      for (int r = 0; r < 4; ++r)
        ((float*)(A + (size_t)(m * 16 + quad * 4 + r) * 392))[col] =
            fmaxf(acc2[m][r] + bb, 0.f);
  }
  __syncthreads();
  if (gr < n) {
    const float* F = (const float*)(A + (size_t)rl * 392);
    float* hrow = hidden + (size_t)gr * DD + c0;
#pragma unroll
    for (int i = 0; i < 4; ++i) {
      float4 v = *(const float4*)(F + c0 + i * 4);
      float4 h = *(const float4*)(hrow + i * 4);
      h.x += v.x; h.y += v.y; h.z += v.z; h.w += v.w;
      *(float4*)(hrow + i * 4) = h;
    }
  }
}

extern "C" void kernel_launch(void* const* d_in, const int* in_sizes, int n_in,
                              void* d_out, int out_size, void* d_ws, size_t ws_size,
                              hipStream_t stream) {
  const float* batch  = (const float*)d_in[0];
  const int*   selfI  = (const int*)d_in[1];
  const int*   parI   = (const int*)d_in[2];
  const float* rootM  = (const float*)d_in[3];
  const float* leafM  = (const float*)d_in[4];
  const float* startT = (const float*)d_in[5];
  const float* endT   = (const float*)d_in[6];
  const float* Vw1 = (const float*)d_in[7],  *Vb1 = (const float*)d_in[8];
  const float* Vw2 = (const float*)d_in[9],  *Vb2 = (const float*)d_in[10];
  const float* Ew1 = (const float*)d_in[11], *Eb1 = (const float*)d_in[12];
  const float* Ew2 = (const float*)d_in[13], *Eb2 = (const float*)d_in[14];
  const float* Pw1 = (const float*)d_in[15], *Pb1 = (const float*)d_in[16];
  const float* Pw2 = (const float*)d_in[17], *Pb2 = (const float*)d_in[18];
  const float* Cw1 = (const float*)d_in[19], *Cb1 = (const float*)d_in[20];
  const float* Cw2 = (const float*)d_in[21], *Cb2 = (const float*)d_in[22];
  const float* Aw1 = (const float*)d_in[23], *Ab1 = (const float*)d_in[24];
  const float* Aw2 = (const float*)d_in[25], *Ab2 = (const float*)d_in[26];

  const int N = in_sizes[3];
  const int E = in_sizes[1];
  float* out = (float*)d_out;

  char* p = (char*)d_ws;
  auto nxt = [&](size_t sz) { char* r = p; p += (sz + 255) & ~(size_t)255; return r; };
  unsigned short* SpE = (unsigned short*)nxt((size_t)E * DD * 2);
  unsigned short* ScE = (unsigned short*)nxt((size_t)E * DD * 2);
  int* degP = (int*)nxt((size_t)N * 4);
  int* degC = (int*)nxt((size_t)N * 4);
  int* offP = (int*)nxt((size_t)N * 4);
  int* offC = (int*)nxt((size_t)N * 4);
  int* curP = (int*)nxt((size_t)N * 4);
  int* curC = (int*)nxt((size_t)N * 4);
  int* posP = (int*)nxt((size_t)E * 4);
  int* posC = (int*)nxt((size_t)E * 4);
  int* partA = (int*)nxt(4096);
  int* partB = (int*)nxt(4096);
  unsigned short* Vw1t = (unsigned short*)nxt((size_t)128 * 256 * 2);
  unsigned short* Vw2t = (unsigned short*)nxt((size_t)256 * 128 * 2);
  unsigned short* Pw1t = (unsigned short*)nxt((size_t)256 * 256 * 2);
  unsigned short* Pw2t = (unsigned short*)nxt((size_t)256 * 128 * 2);
  unsigned short* Cw1t = (unsigned short*)nxt((size_t)256 * 256 * 2);
  unsigned short* Cw2t = (unsigned short*)nxt((size_t)256 * 128 * 2);
  unsigned short* Aw1t = (unsigned short*)nxt((size_t)384 * 256 * 2);
  unsigned short* Aw2t = (unsigned short*)nxt((size_t)256 * 128 * 2);
  float* b1P = (float*)nxt(256 * 4);
  float* b1C = (float*)nxt(256 * 4);
  // total ws usage ~137 MB (proven-safe envelope)

  hipMemsetAsync(degP, 0, (size_t)N * 4, stream);
  hipMemsetAsync(degC, 0, (size_t)N * 4, stream);

  auto blk = [](int total) { return dim3((total + 255) / 256); };
  wconv<<<blk(128 * 256), 256, 0, stream>>>(Vw1, Vw1t, 128, 256, 0);
  wconv<<<blk(256 * 128), 256, 0, stream>>>(Vw2, Vw2t, 256, 128, 0);
  wconv<<<blk(256 * 256), 256, 0, stream>>>(Pw1, Pw1t, 256, 256, 128);  // half-swap
  wconv<<<blk(256 * 128), 256, 0, stream>>>(Pw2, Pw2t, 256, 128, 0);
  wconv<<<blk(256 * 256), 256, 0, stream>>>(Cw1, Cw1t, 256, 256, 0);
  wconv<<<blk(256 * 128), 256, 0, stream>>>(Cw2, Cw2t, 256, 128, 0);
  wconv<<<blk(384 * 256), 256, 0, stream>>>(Aw1, Aw1t, 384, 256, 0);
  wconv<<<blk(256 * 128), 256, 0, stream>>>(Aw2, Aw2t, 256, 128, 0);

  prep_bias<<<1, 256, 0, stream>>>(Ew1, Eb1, Ew2, Eb2, Pw1, Pb1, Cw1, Cb1, b1P, b1C);
  count_k<<<blk(E), 256, 0, stream>>>(selfI, parI, degP, degC, E);

  int NB = (N + 1023) / 1024;
  scan1<<<NB, 256, 0, stream>>>(degP, offP, partA, N);
  scan1<<<NB, 256, 0, stream>>>(degC, offC, partB, N);
  scan2<<<1, 256, 0, stream>>>(partA, NB);
  scan2<<<1, 256, 0, stream>>>(partB, NB);
  scan3<<<blk(N), 256, 0, stream>>>(offP, partA, N);
  scan3<<<blk(N), 256, 0, stream>>>(offC, partB, N);
  copy2<<<blk(N), 256, 0, stream>>>(offP, curP, offC, curC, N);
  pos_k<<<blk(E), 256, 0, stream>>>(selfI, parI, curP, curC, posP, posC, E);

  dim3 gN((N + 63) / 64), gE((E + 63) / 64);
  v_kernel<<<gN, 512, 0, stream>>>(batch, Vw1t, Vw2t, Vb1, Vb2, out, N);

  for (int hop = 0; hop < 3; ++hop) {
    edge_kernel<<<gE, 512, 0, stream>>>(out, selfI, parI, posP, posC,
                                        Pw1t, Pw2t, Cw1t, Cw2t, b1P, b1C, Pb2, Cb2,
                                        SpE, ScE, E);
    node_kernel<<<gN, 512, 0, stream>>>(out, SpE, ScE, offP, degP, offC, degC,
                                        rootM, leafM, startT, endT,
                                        Aw1t, Aw2t, Ab1, Ab2, N);
  }
}